// Round 1
// baseline (579.081 us; speedup 1.0000x reference)
//
#include <hip/hip_runtime.h>

// CrossAttentionSpatial: GN(x), GN(condA), Q/K/V 1x1 convs, 4096x4096 attention.
// fp16 MFMA (16x16x32) throughout; fp32 accumulate; no-max-sub online softmax.
// B=8, C=256, E=512, N=M=4096, GROUPS=32.

typedef _Float16 half8 __attribute__((ext_vector_type(8)));
typedef _Float16 half4v __attribute__((ext_vector_type(4)));
typedef float f32x4 __attribute__((ext_vector_type(4)));

#define MFMA16(a, b, c) __builtin_amdgcn_mfma_f32_16x16x32_f16((a), (b), (c), 0, 0, 0)

// ---------------------------------------------------------------------------
// Kernel 1: group stats. Groups are contiguous segments: x: 256 groups x 32768
// floats; condA: 256 groups x 65536. One block per group.
// ---------------------------------------------------------------------------
__global__ __launch_bounds__(256) void stats_kernel(
    const float* __restrict__ x, const float* __restrict__ condA,
    float* __restrict__ sx, float* __restrict__ sc) {
  int id = blockIdx.x;
  const float4* src;
  int nf4;
  float* dst;
  float inv_n;
  if (id < 256) {
    src = (const float4*)(x + (size_t)id * 32768);
    nf4 = 8192;
    dst = sx + id * 2;
    inv_n = 1.0f / 32768.0f;
  } else {
    int j = id - 256;
    src = (const float4*)(condA + (size_t)j * 65536);
    nf4 = 16384;
    dst = sc + j * 2;
    inv_n = 1.0f / 65536.0f;
  }
  int t = threadIdx.x;
  float s = 0.f, s2 = 0.f;
  for (int i = t; i < nf4; i += 256) {
    float4 v = src[i];
    s += v.x + v.y + v.z + v.w;
    s2 += v.x * v.x + v.y * v.y + v.z * v.z + v.w * v.w;
  }
#pragma unroll
  for (int m = 1; m <= 32; m <<= 1) {
    s += __shfl_xor(s, m, 64);
    s2 += __shfl_xor(s2, m, 64);
  }
  __shared__ float red[8];
  int w = t >> 6;
  if ((t & 63) == 0) { red[w * 2] = s; red[w * 2 + 1] = s2; }
  __syncthreads();
  if (t == 0) {
    float S = red[0] + red[2] + red[4] + red[6];
    float S2 = red[1] + red[3] + red[5] + red[7];
    float mu = S * inv_n;
    float var = S2 * inv_n - mu * mu;
    dst[0] = mu;
    dst[1] = rsqrtf(var + 1e-5f);
  }
}

// ---------------------------------------------------------------------------
// Kernel 2: normalize + transpose. src [B][CH][4096] fp32 -> dst [B][4096][CH]
// fp16.  64x64 tile via LDS (row pad 65 -> conflict-free scalar ops).
// Grid: B(8) * ntile(64) * ctile(CH/64). GS = channels per group.
// ---------------------------------------------------------------------------
template <int CH, int GS>
__global__ __launch_bounds__(256) void ntrans_kernel(
    const float* __restrict__ src, const float* __restrict__ stats,
    const float* __restrict__ gw, const float* __restrict__ gb,
    _Float16* __restrict__ dst) {
  int bid = blockIdx.x;
  int b = bid & 7, nt = (bid >> 3) & 63, ctile = bid >> 9;
  int n0 = nt * 64, c0 = ctile * 64;
  int t = threadIdx.x;
  __shared__ float tile[64][65];

  int cl = t >> 2;  // 0..63 (channel within tile)
  int c = c0 + cl;
  const float* st = stats + ((size_t)b * 32 + (c / GS)) * 2;
  float mu = st[0], rs = st[1];
  float a = rs * gw[c];
  float bb = gb[c] - mu * a;
  const float* srow = src + ((size_t)(b * CH + c)) * 4096 + n0 + (t & 3) * 16;
#pragma unroll
  for (int i = 0; i < 4; i++) {
    float4 v = *(const float4*)(srow + 4 * i);
    int nn = (t & 3) * 16 + 4 * i;
    tile[cl][nn + 0] = v.x * a + bb;
    tile[cl][nn + 1] = v.y * a + bb;
    tile[cl][nn + 2] = v.z * a + bb;
    tile[cl][nn + 3] = v.w * a + bb;
  }
  __syncthreads();
  int nl = t >> 2;  // row of output
  half8 o0v, o1v;
#pragma unroll
  for (int i = 0; i < 8; i++) o0v[i] = (_Float16)tile[(t & 3) * 16 + i][nl];
#pragma unroll
  for (int i = 0; i < 8; i++) o1v[i] = (_Float16)tile[(t & 3) * 16 + 8 + i][nl];
  _Float16* drow = dst + ((size_t)b * 4096 + n0 + nl) * CH + c0 + (t & 3) * 16;
  *(half8*)drow = o0v;
  *((half8*)drow + 1) = o1v;
}

// ---------------------------------------------------------------------------
// Kernel 3: weight fp32 -> fp16. 65536 (wq) + 131072 (wk) + 131072 (wv).
// ---------------------------------------------------------------------------
__global__ __launch_bounds__(256) void wconv_kernel(
    const float* __restrict__ wq, const float* __restrict__ wk,
    const float* __restrict__ wv, _Float16* __restrict__ dq,
    _Float16* __restrict__ dk, _Float16* __restrict__ dv) {
  int i = blockIdx.x * 256 + threadIdx.x;
  if (i < 65536) dq[i] = (_Float16)wq[i];
  int j = i - 65536;
  if (j >= 0 && j < 131072) dk[j] = (_Float16)wk[j];
  int k = i - 196608;
  if (k >= 0 && k < 131072) dv[k] = (_Float16)wv[k];
}

// ---------------------------------------------------------------------------
// Kernel 4: projection GEMM, LDS-free. A [B][4096][CIN] fp16 (rows contiguous
// -> direct A-frags). W [256][CIN] fp16 (rows contiguous -> direct B-frags,
// L2-hot). Block: 64 rows x 128 cols (wave = 16 rows x 128 cols, 8 col-tiles).
// MODE 0: Q, scale (acc+bias)/16, store [B][4096][256].
// MODE 1: K,            store [B][4096][256].
// MODE 2: V,            store [B][256][4096] (channel-major, packed 8B).
// Grid: 8 * 64 * 2 = 1024.
// ---------------------------------------------------------------------------
template <int CIN, int MODE>
__global__ __launch_bounds__(256, 2) void proj_kernel(
    const _Float16* __restrict__ A, const _Float16* __restrict__ W,
    const float* __restrict__ bias, _Float16* __restrict__ out) {
  int bid = blockIdx.x;
  int b = bid & 7, nt = (bid >> 3) & 63, ot = bid >> 9;
  int n0 = nt * 64, o0 = ot * 128;
  int t = threadIdx.x, l = t & 63, w = t >> 6;
  int c15 = l & 15, q = l >> 4;
  int row = n0 + w * 16 + c15;

  const half8* arow = (const half8*)(A + ((size_t)b * 4096 + row) * CIN) + q;
  const half8* wrows[8];
#pragma unroll
  for (int ct = 0; ct < 8; ct++)
    wrows[ct] = (const half8*)(W + (size_t)(o0 + ct * 16 + c15) * CIN) + q;

  f32x4 acc[8] = {};
#pragma unroll 4
  for (int ks = 0; ks < CIN / 32; ks++) {
    half8 af = arow[ks * 4];
#pragma unroll
    for (int ct = 0; ct < 8; ct++) {
      half8 bf = wrows[ct][ks * 4];
      acc[ct] = MFMA16(af, bf, acc[ct]);
    }
  }
#pragma unroll
  for (int ct = 0; ct < 8; ct++) {
    int o = o0 + ct * 16 + c15;
    float bs = bias[o];
    if constexpr (MODE == 2) {
      half4v pv4;
#pragma unroll
      for (int r = 0; r < 4; r++) pv4[r] = (_Float16)(acc[ct][r] + bs);
      *(half4v*)(out + ((size_t)b * 256 + o) * 4096 + n0 + w * 16 + 4 * q) = pv4;
    } else {
#pragma unroll
      for (int r = 0; r < 4; r++) {
        float v = acc[ct][r] + bs;
        if constexpr (MODE == 0) v *= 0.0625f;  // 1/sqrt(C), folded into Q
        out[((size_t)b * 4096 + n0 + w * 16 + 4 * q + r) * 256 + o] = (_Float16)v;
      }
    }
  }
}

// ---------------------------------------------------------------------------
// Kernel 5: attention. Per block: 64 query rows, loop M in 64-row tiles.
// Q[B][N][256] f16 (A-frags in regs, loaded once). K[B][M][256] f16 staged to
// LDS [m][c]; V[B][256][M] f16 staged to same LDS buffer [c][m] after S-phase
// (shared 32KB buffer -> 40KB total static LDS). P round-trips through 8KB
// LDS for C-layout -> A-layout. XOR-swizzle (16B granules) on all LDS layouts
// -> conflict-free b128. No max-subtraction (logits bounded ~1.7): l = sum
// exp accumulated per lane, O normalized in epilogue. Out fp32 [B][C][N].
// Grid: 8 * 64 = 512 (batch in low bits for XCD/L2 locality).
// ---------------------------------------------------------------------------
__global__ __launch_bounds__(256, 2) void attn_kernel(
    const _Float16* __restrict__ Q, const _Float16* __restrict__ K,
    const _Float16* __restrict__ V, float* __restrict__ out) {
  int bid = blockIdx.x;
  int b = bid & 7, nt = bid >> 3;
  int n0 = nt * 64;
  int t = threadIdx.x, l = t & 63, w = t >> 6;
  int c15 = l & 15, q = l >> 4;

  __shared__ __align__(16) _Float16 kv[64 * 256];   // 32KB: K[m][c] then V[c][m]
  __shared__ __align__(16) _Float16 plds[64 * 64];  // 8KB: P[n][m]

  // Q fragments: rows n0 + 16w + (l&15), k = 32ks + 8q
  half8 qf[8];
  {
    const half8* qrow =
        (const half8*)(Q + ((size_t)b * 4096 + n0 + w * 16 + c15) * 256) + q;
#pragma unroll
    for (int ks = 0; ks < 8; ks++) qf[ks] = qrow[ks * 4];
  }

  f32x4 acc_o[16] = {};
  float l_sum[4] = {0.f, 0.f, 0.f, 0.f};

  // K staging: thread t covers row m=t>>2, interleaved 16B chunks (t&3)+4i
  const int km = t >> 2, kc = t & 3;
  const half8* kbase = (const half8*)(K + ((size_t)b * 4096 + km) * 256) + kc;
  // V staging: 8 passes, row c = 32p + (t>>3), chunk t&7
  const int vt8 = t & 7, vrow = t >> 3;
  const half8* vbase = (const half8*)(V + ((size_t)b * 256 + vrow) * 4096) + vt8;

  for (int mt = 0; mt < 64; mt++) {
    int m0 = mt * 64;
    // ---- stage K tile [64 m][256 c], swizzled granule = g ^ (m&7) ----
    {
      const half8* kg = kbase + m0 * 32;  // + m0 rows (m0*256 halfs)
      half8* dst = (half8*)kv;
#pragma unroll
      for (int i = 0; i < 8; i++) {
        half8 v = kg[4 * i];
        dst[km * 32 + ((kc + 4 * i) ^ (km & 7))] = v;
      }
    }
    __syncthreads();  // K visible
    // ---- S = Q K^T (wave: 16 rows x 64 cols) ----
    f32x4 s[4];
#pragma unroll
    for (int ct = 0; ct < 4; ct++) {
      f32x4 a = {0.f, 0.f, 0.f, 0.f};
      int m = ct * 16 + c15;
#pragma unroll
      for (int ks = 0; ks < 8; ks++) {
        int g = (4 * ks + q) ^ (m & 7);
        half8 kf = *(const half8*)&kv[m * 256 + g * 8];
        a = MFMA16(qf[ks], kf, a);
      }
      s[ct] = a;
    }
    // ---- P = exp(S); accumulate row-sums (full rows: cols = 16ct + lane) ----
    _Float16 pv[16];
#pragma unroll
    for (int ct = 0; ct < 4; ct++) {
#pragma unroll
      for (int r = 0; r < 4; r++) {
        float e = __expf(s[ct][r]);
        l_sum[r] += e;
        pv[ct * 4 + r] = (_Float16)e;
      }
    }
    __syncthreads();  // all waves done reading K from kv
    // ---- stage V tile [256 c][64 m] into kv; write P ----
    {
      const half8* vg = vbase + m0 / 8;
#pragma unroll
      for (int p = 0; p < 8; p++) {
        int c = p * 32 + vrow;
        half8 v = vg[p * 16384];  // +32 rows * 4096 halfs
        ((half8*)kv)[c * 8 + (vt8 ^ (c & 7))] = v;
      }
    }
#pragma unroll
    for (int ct = 0; ct < 4; ct++) {
#pragma unroll
      for (int r = 0; r < 4; r++) {
        int n = w * 16 + 4 * q + r;
        int m = ct * 16 + c15;
        plds[n * 64 + ((m >> 3) ^ (n & 7)) * 8 + (m & 7)] = pv[ct * 4 + r];
      }
    }
    __syncthreads();  // V & P visible
    // ---- O += P V ----
    half8 pf[2];
    {
      int n = w * 16 + c15;
#pragma unroll
      for (int ms = 0; ms < 2; ms++) {
        int g = (4 * ms + q) ^ (n & 7);
        pf[ms] = *(const half8*)&plds[n * 64 + g * 8];
      }
    }
#pragma unroll
    for (int ct = 0; ct < 16; ct++) {
      int c = ct * 16 + c15;
#pragma unroll
      for (int ms = 0; ms < 2; ms++) {
        int g = (4 * ms + q) ^ (c & 7);
        half8 vf = *(const half8*)&kv[c * 64 + g * 8];
        acc_o[ct] = MFMA16(pf[ms], vf, acc_o[ct]);
      }
    }
    __syncthreads();  // all done reading kv/plds before next K stage
  }

  // ---- epilogue: finish row sums (reduce over 16 col-lanes), normalize ----
#pragma unroll
  for (int r = 0; r < 4; r++) {
    float v = l_sum[r];
    v += __shfl_xor(v, 1, 64);
    v += __shfl_xor(v, 2, 64);
    v += __shfl_xor(v, 4, 64);
    v += __shfl_xor(v, 8, 64);
    l_sum[r] = 1.0f / v;
  }
#pragma unroll
  for (int ct = 0; ct < 16; ct++) {
    int c = ct * 16 + c15;
    float4 o4;
    o4.x = acc_o[ct][0] * l_sum[0];
    o4.y = acc_o[ct][1] * l_sum[1];
    o4.z = acc_o[ct][2] * l_sum[2];
    o4.w = acc_o[ct][3] * l_sum[3];
    *(float4*)(out + ((size_t)b * 256 + c) * 4096 + n0 + w * 16 + 4 * q) = o4;
  }
}

// ---------------------------------------------------------------------------
extern "C" void kernel_launch(void* const* d_in, const int* in_sizes, int n_in,
                              void* d_out, int out_size, void* d_ws,
                              size_t ws_size, hipStream_t stream) {
  const float* x = (const float*)d_in[0];
  const float* condA = (const float*)d_in[1];
  const float* gxw = (const float*)d_in[2];
  const float* gxb = (const float*)d_in[3];
  const float* gcw = (const float*)d_in[4];
  const float* gcb = (const float*)d_in[5];
  const float* qw = (const float*)d_in[6];
  const float* qb = (const float*)d_in[7];
  const float* kw = (const float*)d_in[8];
  const float* kb = (const float*)d_in[9];
  const float* vw = (const float*)d_in[10];
  const float* vb = (const float*)d_in[11];
  float* out = (float*)d_out;

  char* ws = (char*)d_ws;
  float* statsx = (float*)(ws);                     // 2048 B
  float* statsc = (float*)(ws + 2048);              // 2048 B
  _Float16* wqh = (_Float16*)(ws + 4096);           // 128 KB
  _Float16* wkh = (_Float16*)(ws + 135168);         // 256 KB
  _Float16* wvh = (_Float16*)(ws + 397312);         // 256 KB
  char* p = ws + 659456;
  _Float16* hxT = (_Float16*)p; p += (size_t)8 * 4096 * 256 * 2;  // 16 MB
  _Float16* h1T = (_Float16*)p; p += (size_t)8 * 4096 * 512 * 2;  // 32 MB
  _Float16* Qh = (_Float16*)p;  p += (size_t)8 * 4096 * 256 * 2;  // 16 MB
  _Float16* Kh = (_Float16*)p;  p += (size_t)8 * 4096 * 256 * 2;  // 16 MB
  _Float16* Vh = (_Float16*)p;                                    // 16 MB

  stats_kernel<<<512, 256, 0, stream>>>(x, condA, statsx, statsc);
  ntrans_kernel<256, 8><<<2048, 256, 0, stream>>>(x, statsx, gxw, gxb, hxT);
  ntrans_kernel<512, 16><<<4096, 256, 0, stream>>>(condA, statsc, gcw, gcb, h1T);
  wconv_kernel<<<1280, 256, 0, stream>>>(qw, kw, vw, wqh, wkh, wvh);
  proj_kernel<256, 0><<<1024, 256, 0, stream>>>(hxT, wqh, qb, Qh);
  proj_kernel<512, 1><<<1024, 256, 0, stream>>>(h1T, wkh, kb, Kh);
  proj_kernel<512, 2><<<1024, 256, 0, stream>>>(h1T, wvh, vb, Vh);
  attn_kernel<<<512, 256, 0, stream>>>(Qh, Kh, Vh, out);
}